// Round 6
// baseline (982.666 us; speedup 1.0000x reference)
//
#include <hip/hip_runtime.h>
#include <cstdint>

#define NNODES 100000
#define NEDGES 1200000
#define INF 64
#define OUTF 32
#define SHIFT 6
#define BNODES 64                                  // nodes per bucket
#define NBUCK ((NNODES + BNODES - 1) / BNODES)     // 1563; bucket = dst >> 6
#define BCAP 1024                                  // slots/bucket (mean 768, sd 28 -> +9 sigma)
#define BIN_EPT 8
#define BIN_THREADS (NEDGES / BIN_EPT)             // 150000
#define CUR_PAD 16                                 // 64B-padded global cursors
#define ACCS 33                                    // LDS acc row stride (bank spread)

// ---- cursor init: gcur[b] = b*BCAP ----
__global__ __launch_bounds__(256) void k_initcur(int* __restrict__ gcur) {
    int i = blockIdx.x * 256 + threadIdx.x;
    if (i < NBUCK) gcur[i * CUR_PAD] = i * BCAP;
}

// ---- pass 1: bin edges into fixed-capacity buckets, packed (dlow<<17 | src) ----
__global__ __launch_bounds__(256) void k_bin(const int4* __restrict__ src4,
                                             const int4* __restrict__ dst4,
                                             int* __restrict__ gcur,
                                             unsigned* __restrict__ packed) {
    __shared__ int cnt[NBUCK];
    __shared__ int base[NBUCK];
    int tid = threadIdx.x;
    for (int i = tid; i < NBUCK; i += 256) cnt[i] = 0;
    __syncthreads();
    int gid = blockIdx.x * 256 + tid;
    bool act = gid < BIN_THREADS;
    int4 s4[2], d4[2];
    if (act) {
#pragma unroll
        for (int k = 0; k < 2; ++k) {
            s4[k] = src4[(size_t)gid * 2 + k];
            d4[k] = dst4[(size_t)gid * 2 + k];
            atomicAdd(&cnt[d4[k].x >> SHIFT], 1);
            atomicAdd(&cnt[d4[k].y >> SHIFT], 1);
            atomicAdd(&cnt[d4[k].z >> SHIFT], 1);
            atomicAdd(&cnt[d4[k].w >> SHIFT], 1);
        }
    }
    __syncthreads();
    for (int i = tid; i < NBUCK; i += 256) {
        int c = cnt[i];
        base[i] = c ? atomicAdd(&gcur[i * CUR_PAD], c) : 0;
        cnt[i] = 0;
    }
    __syncthreads();
    if (act) {
#pragma unroll
        for (int k = 0; k < 2; ++k) {
            int ss[4] = {s4[k].x, s4[k].y, s4[k].z, s4[k].w};
            int dd[4] = {d4[k].x, d4[k].y, d4[k].z, d4[k].w};
#pragma unroll
            for (int j = 0; j < 4; ++j) {
                int b = dd[j] >> SHIFT;
                int rel = atomicAdd(&cnt[b], 1);
                packed[base[b] + rel] =
                    ((unsigned)(dd[j] & (BNODES - 1)) << 17) | (unsigned)ss[j];
            }
        }
    }
}

// ---- degrees (LDS histogram per bucket) -> norm ----
__global__ __launch_bounds__(256) void k_degnorm(const unsigned* __restrict__ packed,
                                                 const int* __restrict__ gcur,
                                                 float* __restrict__ norm) {
    __shared__ int deg[BNODES];
    int b = blockIdx.x, tid = threadIdx.x;
    int node0 = b << SHIFT;
    int nn = (NNODES - node0 < BNODES) ? (NNODES - node0) : BNODES;
    if (tid < BNODES) deg[tid] = 0;
    __syncthreads();
    int ebase = b * BCAP;
    int nedge = gcur[b * CUR_PAD] - ebase;
    for (int i = tid; i < nedge; i += 256)
        atomicAdd(&deg[packed[ebase + i] >> 17], 1);
    __syncthreads();
    if (tid < nn) {
        int d = deg[tid];
        norm[node0 + tid] = rsqrtf(d < 1 ? 1.0f : (float)d);
    }
}

// ---- u0 = norm .* (X @ W^T) ----
__global__ __launch_bounds__(256) void k_project(const float* __restrict__ feat,
                                                 const float* __restrict__ W,
                                                 const float* __restrict__ norm,
                                                 float* __restrict__ u0) {
    __shared__ float Ws[OUTF][INF + 1];
    __shared__ float Fs[8][INF];
    int tid = threadIdx.x;
    for (int i = tid; i < OUTF * INF; i += 256) Ws[i / INF][i % INF] = W[i];
    int node0 = blockIdx.x * 8;
    for (int i = tid; i < 8 * INF; i += 256) {
        int n = node0 + i / INF;
        Fs[i / INF][i % INF] = (n < NNODES) ? feat[(size_t)n * INF + (i % INF)] : 0.0f;
    }
    __syncthreads();
    int ln = tid >> 5, of = tid & 31;
    int n = node0 + ln;
    if (n < NNODES) {
        float acc = 0.0f;
#pragma unroll
        for (int k = 0; k < INF; ++k) acc += Fs[ln][k] * Ws[of][k];
        u0[(size_t)n * OUTF + of] = acc * norm[n];
    }
}

// ---- one hop, edge-parallel per bucket with LDS accumulation ----
// uout[d] = w(d) * sum_{e in bucket, dst=d} uin[src(e)]; w = norm^2 (mid) or
// norm (last, + bias). 8 lanes/edge, 4-deep gather pipeline, ds_add_f32 acc.
template <bool LAST>
__global__ __launch_bounds__(256) void k_hop(const float4* __restrict__ uin,
                                             float* __restrict__ uout,
                                             const unsigned* __restrict__ packed,
                                             const int* __restrict__ gcur,
                                             const float* __restrict__ norm,
                                             const float* __restrict__ bias) {
    __shared__ float acc[BNODES * ACCS];
    __shared__ float ns[BNODES];
    int b = blockIdx.x, tid = threadIdx.x;
    int node0 = b << SHIFT;
    int nn = (NNODES - node0 < BNODES) ? (NNODES - node0) : BNODES;
    for (int i = tid; i < BNODES * ACCS; i += 256) acc[i] = 0.0f;
    if (tid < nn) ns[tid] = norm[node0 + tid];
    __syncthreads();
    int ebase = b * BCAP;
    int nedge = gcur[b * CUR_PAD] - ebase;
    int g = tid >> 3, l8 = tid & 7;
    for (int i = g; i < nedge; i += 128) {
        bool b1 = i + 32 < nedge, b2 = i + 64 < nedge, b3 = i + 96 < nedge;
        unsigned pk0 = packed[ebase + i];
        unsigned pk1 = b1 ? packed[ebase + i + 32] : pk0;
        unsigned pk2 = b2 ? packed[ebase + i + 64] : pk0;
        unsigned pk3 = b3 ? packed[ebase + i + 96] : pk0;
        float4 v0 = uin[(size_t)(pk0 & 0x1FFFFu) * 8 + l8];
        float4 v1 = uin[(size_t)(pk1 & 0x1FFFFu) * 8 + l8];
        float4 v2 = uin[(size_t)(pk2 & 0x1FFFFu) * 8 + l8];
        float4 v3 = uin[(size_t)(pk3 & 0x1FFFFu) * 8 + l8];
        float* a0 = &acc[(pk0 >> 17) * ACCS + l8 * 4];
        atomicAdd(a0 + 0, v0.x); atomicAdd(a0 + 1, v0.y);
        atomicAdd(a0 + 2, v0.z); atomicAdd(a0 + 3, v0.w);
        if (b1) {
            float* a1 = &acc[(pk1 >> 17) * ACCS + l8 * 4];
            atomicAdd(a1 + 0, v1.x); atomicAdd(a1 + 1, v1.y);
            atomicAdd(a1 + 2, v1.z); atomicAdd(a1 + 3, v1.w);
        }
        if (b2) {
            float* a2 = &acc[(pk2 >> 17) * ACCS + l8 * 4];
            atomicAdd(a2 + 0, v2.x); atomicAdd(a2 + 1, v2.y);
            atomicAdd(a2 + 2, v2.z); atomicAdd(a2 + 3, v2.w);
        }
        if (b3) {
            float* a3 = &acc[(pk3 >> 17) * ACCS + l8 * 4];
            atomicAdd(a3 + 0, v3.x); atomicAdd(a3 + 1, v3.y);
            atomicAdd(a3 + 2, v3.z); atomicAdd(a3 + 3, v3.w);
        }
    }
    __syncthreads();
    for (int e = tid; e < nn * OUTF; e += 256) {
        int dl = e >> 5, f = e & 31;
        float w = ns[dl];
        if (!LAST) w *= w;
        float val = acc[dl * ACCS + f] * w;
        if (LAST) val += bias[f];
        uout[(size_t)node0 * OUTF + e] = val;
    }
}

extern "C" void kernel_launch(void* const* d_in, const int* in_sizes, int n_in,
                              void* d_out, int out_size, void* d_ws, size_t ws_size,
                              hipStream_t stream) {
    const float* feat = (const float*)d_in[0];
    const int*   src  = (const int*)d_in[1];
    const int*   dst  = (const int*)d_in[2];
    const float* W    = (const float*)d_in[3];
    const float* b    = (const float*)d_in[4];
    float* out = (float*)d_out;

    char* ws = (char*)d_ws;
    size_t off = 0;
    auto alloc = [&](size_t bytes) {
        void* p = ws + off;
        off = (off + bytes + 255) & ~(size_t)255;
        return p;
    };
    float*    norm   = (float*)alloc((size_t)NNODES * 4);
    int*      gcur   = (int*)alloc((size_t)NBUCK * CUR_PAD * 4);
    unsigned* packed = (unsigned*)alloc((size_t)NBUCK * BCAP * 4);
    float*    h0     = (float*)alloc((size_t)NNODES * OUTF * 4);
    float*    h1     = (float*)alloc((size_t)NNODES * OUTF * 4);

    // ---- bucketed edge binning ----
    k_initcur<<<(NBUCK + 255) / 256, 256, 0, stream>>>(gcur);
    k_bin<<<(BIN_THREADS + 255) / 256, 256, 0, stream>>>(
        (const int4*)src, (const int4*)dst, gcur, packed);
    k_degnorm<<<NBUCK, 256, 0, stream>>>(packed, gcur, norm);

    // ---- project 64 -> 32, pre-scaled by norm ----
    k_project<<<(NNODES + 7) / 8, 256, 0, stream>>>(feat, W, norm, h0);

    // ---- 4 edge-parallel hops ----
    k_hop<false><<<NBUCK, 256, 0, stream>>>((const float4*)h0, h1, packed, gcur,
                                            norm, nullptr);
    k_hop<false><<<NBUCK, 256, 0, stream>>>((const float4*)h1, h0, packed, gcur,
                                            norm, nullptr);
    k_hop<false><<<NBUCK, 256, 0, stream>>>((const float4*)h0, h1, packed, gcur,
                                            norm, nullptr);
    k_hop<true><<<NBUCK, 256, 0, stream>>>((const float4*)h1, out, packed, gcur,
                                           norm, b);
}

// Round 7
// 154.937 us; speedup vs baseline: 6.3424x; 6.3424x over previous
//
#include <hip/hip_runtime.h>
#include <cstdint>

#define NNODES 100000
#define NEDGES 1200000
#define INF 64
#define OUTF 32
#define SCAN_B 256
#define NBUCK ((NNODES + SCAN_B - 1) / SCAN_B)   // 391; bucket b = dst >> 8
#define PLACE_CAP 4608                            // fixed slots/bucket (R3/R4-verified)
#define BIN_EPT 16
#define BIN_THREADS (NEDGES / BIN_EPT)            // 75000
#define BIN_BLOCKS ((BIN_THREADS + 255) / 256)    // 293
#define PROJ_NPB 16
#define PROJ_BLOCKS (NNODES / PROJ_NPB)           // 6250 (exact)
#define CUR_PAD 16                                // 64B-padded global cursors

// ---- cursor init: gcur[b] = b*PLACE_CAP ----
__global__ __launch_bounds__(256) void k_initcur(int* __restrict__ gcur) {
    int i = blockIdx.x * 256 + threadIdx.x;
    if (i < NBUCK) gcur[i * CUR_PAD] = i * PLACE_CAP;
}

// ---- fused: blocks [0,BIN_BLOCKS) bin edges; rest project h0 = X@W^T ----
// Projection is norm-independent (unscaled h0); hop1 applies norm[src].
__global__ __launch_bounds__(256) void k_binproj(const int4* __restrict__ src4,
                                                 const int4* __restrict__ dst4,
                                                 int* __restrict__ gcur,
                                                 unsigned* __restrict__ packed,
                                                 const float4* __restrict__ feat4,
                                                 const float4* __restrict__ W4,
                                                 float2* __restrict__ h0_2) {
    __shared__ __align__(16) char smem[12480];
    int tid = threadIdx.x;
    if (blockIdx.x < BIN_BLOCKS) {
        int* cnt = (int*)smem;
        int* base = cnt + NBUCK;
        for (int i = tid; i < NBUCK; i += 256) cnt[i] = 0;
        __syncthreads();
        int gid = blockIdx.x * 256 + tid;
        bool act = gid < BIN_THREADS;
        int4 s4[4], d4[4];
        if (act) {
#pragma unroll
            for (int k = 0; k < 4; ++k) {
                s4[k] = src4[(size_t)gid * 4 + k];
                d4[k] = dst4[(size_t)gid * 4 + k];
                atomicAdd(&cnt[d4[k].x >> 8], 1);
                atomicAdd(&cnt[d4[k].y >> 8], 1);
                atomicAdd(&cnt[d4[k].z >> 8], 1);
                atomicAdd(&cnt[d4[k].w >> 8], 1);
            }
        }
        __syncthreads();
        for (int i = tid; i < NBUCK; i += 256) {
            int c = cnt[i];
            base[i] = c ? atomicAdd(&gcur[i * CUR_PAD], c) : 0;
            cnt[i] = 0;
        }
        __syncthreads();
        if (act) {
#pragma unroll
            for (int k = 0; k < 4; ++k) {
                int ss[4] = {s4[k].x, s4[k].y, s4[k].z, s4[k].w};
                int dd[4] = {d4[k].x, d4[k].y, d4[k].z, d4[k].w};
#pragma unroll
                for (int j = 0; j < 4; ++j) {
                    int b = dd[j] >> 8;
                    int rel = atomicAdd(&cnt[b], 1);
                    packed[base[b] + rel] =
                        ((unsigned)(dd[j] & 255) << 17) | (unsigned)ss[j];
                }
            }
        }
    } else {
        float (*Ws)[INF + 1] = (float (*)[INF + 1])smem;                 // [32][65]
        float (*Fs)[INF + 1] = (float (*)[INF + 1])(smem + 8320);       // [16][65]
        int node0 = (blockIdx.x - BIN_BLOCKS) * PROJ_NPB;
        // stage W (2048 floats = 512 float4)
        for (int i = tid; i < 512; i += 256) {
            float4 w = W4[i];
            int f = i * 4, of = f >> 6, k = f & 63;
            Ws[of][k] = w.x; Ws[of][k + 1] = w.y;
            Ws[of][k + 2] = w.z; Ws[of][k + 3] = w.w;
        }
        // stage 16 nodes x 64 feats (each thread: one float4)
        {
            int n = node0 + (tid >> 4), q = tid & 15;
            float4 v = feat4[(size_t)n * 16 + q];
            int c = q * 4;
            Fs[tid >> 4][c] = v.x; Fs[tid >> 4][c + 1] = v.y;
            Fs[tid >> 4][c + 2] = v.z; Fs[tid >> 4][c + 3] = v.w;
        }
        __syncthreads();
        int ln = tid >> 4, n = node0 + ln;
        int of0 = (tid & 15) * 2;
        float a0 = 0.0f, a1 = 0.0f;
#pragma unroll
        for (int k = 0; k < INF; ++k) {
            float f = Fs[ln][k];
            a0 += f * Ws[of0][k];
            a1 += f * Ws[of0 + 1][k];
        }
        h0_2[(size_t)n * 16 + (tid & 15)] = make_float2(a0, a1);
    }
}

// ---- per bucket: degree (LDS), norm, rowse, LDS scatter, coalesced col ----
__global__ __launch_bounds__(256) void k_place(const unsigned* __restrict__ packed,
                                               const int* __restrict__ gcur,
                                               int* __restrict__ col,
                                               int2* __restrict__ rowse,
                                               float* __restrict__ norm) {
    __shared__ unsigned sin_[PLACE_CAP];
    __shared__ int stage[PLACE_CAP];
    __shared__ int deg[SCAN_B];
    __shared__ int rs[SCAN_B];
    int b = blockIdx.x, tid = threadIdx.x;
    int node0 = b * SCAN_B;
    int nn = (NNODES - node0 < SCAN_B) ? (NNODES - node0) : SCAN_B;
    int ebase = b * PLACE_CAP;
    int nedge = gcur[b * CUR_PAD] - ebase;
    deg[tid] = 0;
    __syncthreads();
    for (int i = tid; i < nedge; i += 256) {
        unsigned pk = packed[ebase + i];
        sin_[i] = pk;
        atomicAdd(&deg[pk >> 17], 1);
    }
    __syncthreads();
    int d = deg[tid];
    rs[tid] = d;
    __syncthreads();
    for (int st = 1; st < SCAN_B; st <<= 1) {
        int add = (tid >= st) ? rs[tid - st] : 0;
        __syncthreads();
        rs[tid] += add;
        __syncthreads();
    }
    int myoff = rs[tid] - d;  // exclusive scan within bucket
    if (tid < nn) {
        norm[node0 + tid] = rsqrtf(d < 1 ? 1.0f : (float)d);
        rowse[node0 + tid] = make_int2(ebase + myoff, ebase + myoff + d);
    }
    deg[tid] = myoff;  // reuse as cursor
    __syncthreads();
    for (int i = tid; i < nedge; i += 256) {
        unsigned pk = sin_[i];
        int rel = atomicAdd(&deg[pk >> 17], 1);
        stage[rel] = (int)(pk & 0x1FFFFu);
    }
    __syncthreads();
    for (int i = tid; i < nedge; i += 256) col[ebase + i] = stage[i];
}

// ---- one hop: uout[d] = w(d) * sum_e (FIRST? norm[s]:1)*uin[col[e]] (+bias)
// w = norm^2 (mid) or norm (last). 8 lanes/node, float4 each, 8-deep MLP.
template <bool FIRST, bool LAST>
__global__ __launch_bounds__(256) void k_gather(const float4* __restrict__ uin,
                                                float4* __restrict__ uout,
                                                const int2* __restrict__ rowse,
                                                const int* __restrict__ col,
                                                const float* __restrict__ norm,
                                                const float4* __restrict__ bias4) {
    int t = blockIdx.x * 256 + threadIdx.x;
    int node = t >> 3;
    if (node >= NNODES) return;
    int lane = t & 7;
    int2 se = rowse[node];
    int e = se.x, re = se.y;
    float4 acc = make_float4(0.f, 0.f, 0.f, 0.f);
    for (; e + 7 < re; e += 8) {
        int s0 = col[e],     s1 = col[e + 1], s2 = col[e + 2], s3 = col[e + 3];
        int s4 = col[e + 4], s5 = col[e + 5], s6 = col[e + 6], s7 = col[e + 7];
        float4 a0 = uin[(size_t)s0 * 8 + lane];
        float4 a1 = uin[(size_t)s1 * 8 + lane];
        float4 a2 = uin[(size_t)s2 * 8 + lane];
        float4 a3 = uin[(size_t)s3 * 8 + lane];
        float4 a4 = uin[(size_t)s4 * 8 + lane];
        float4 a5 = uin[(size_t)s5 * 8 + lane];
        float4 a6 = uin[(size_t)s6 * 8 + lane];
        float4 a7 = uin[(size_t)s7 * 8 + lane];
        if (FIRST) {
            float w0 = norm[s0], w1 = norm[s1], w2 = norm[s2], w3 = norm[s3];
            float w4 = norm[s4], w5 = norm[s5], w6 = norm[s6], w7 = norm[s7];
            acc.x += ((w0*a0.x + w1*a1.x) + (w2*a2.x + w3*a3.x)) +
                     ((w4*a4.x + w5*a5.x) + (w6*a6.x + w7*a7.x));
            acc.y += ((w0*a0.y + w1*a1.y) + (w2*a2.y + w3*a3.y)) +
                     ((w4*a4.y + w5*a5.y) + (w6*a6.y + w7*a7.y));
            acc.z += ((w0*a0.z + w1*a1.z) + (w2*a2.z + w3*a3.z)) +
                     ((w4*a4.z + w5*a5.z) + (w6*a6.z + w7*a7.z));
            acc.w += ((w0*a0.w + w1*a1.w) + (w2*a2.w + w3*a3.w)) +
                     ((w4*a4.w + w5*a5.w) + (w6*a6.w + w7*a7.w));
        } else {
            acc.x += ((a0.x + a1.x) + (a2.x + a3.x)) + ((a4.x + a5.x) + (a6.x + a7.x));
            acc.y += ((a0.y + a1.y) + (a2.y + a3.y)) + ((a4.y + a5.y) + (a6.y + a7.y));
            acc.z += ((a0.z + a1.z) + (a2.z + a3.z)) + ((a4.z + a5.z) + (a6.z + a7.z));
            acc.w += ((a0.w + a1.w) + (a2.w + a3.w)) + ((a4.w + a5.w) + (a6.w + a7.w));
        }
    }
    for (; e < re; ++e) {
        int s = col[e];
        float4 a = uin[(size_t)s * 8 + lane];
        float w = FIRST ? norm[s] : 1.0f;
        acc.x += w * a.x; acc.y += w * a.y;
        acc.z += w * a.z; acc.w += w * a.w;
    }
    float nn = norm[node];
    float w = LAST ? nn : nn * nn;
    acc.x *= w; acc.y *= w; acc.z *= w; acc.w *= w;
    if (LAST) {
        float4 bb = bias4[lane];
        acc.x += bb.x; acc.y += bb.y; acc.z += bb.z; acc.w += bb.w;
    }
    uout[(size_t)node * 8 + lane] = acc;
}

extern "C" void kernel_launch(void* const* d_in, const int* in_sizes, int n_in,
                              void* d_out, int out_size, void* d_ws, size_t ws_size,
                              hipStream_t stream) {
    const float* feat = (const float*)d_in[0];
    const int*   src  = (const int*)d_in[1];
    const int*   dst  = (const int*)d_in[2];
    const float* W    = (const float*)d_in[3];
    const float* b    = (const float*)d_in[4];
    float* out = (float*)d_out;

    char* ws = (char*)d_ws;
    size_t off = 0;
    auto alloc = [&](size_t bytes) {
        void* p = ws + off;
        off = (off + bytes + 255) & ~(size_t)255;
        return p;
    };
    float*    norm   = (float*)alloc((size_t)NNODES * 4);
    int2*     rowse  = (int2*)alloc((size_t)NNODES * 8);
    int*      gcur   = (int*)alloc((size_t)NBUCK * CUR_PAD * 4);
    unsigned* packed = (unsigned*)alloc((size_t)NBUCK * PLACE_CAP * 4);
    int*      col    = (int*)alloc((size_t)NBUCK * PLACE_CAP * 4);
    float*    h0     = (float*)alloc((size_t)NNODES * OUTF * 4);
    float*    h1     = (float*)alloc((size_t)NNODES * OUTF * 4);

    // ---- init cursors, then fused {edge binning || projection} ----
    k_initcur<<<(NBUCK + 255) / 256, 256, 0, stream>>>(gcur);
    k_binproj<<<BIN_BLOCKS + PROJ_BLOCKS, 256, 0, stream>>>(
        (const int4*)src, (const int4*)dst, gcur, packed,
        (const float4*)feat, (const float4*)W, (float2*)h0);
    k_place<<<NBUCK, 256, 0, stream>>>(packed, gcur, col, rowse, norm);

    // ---- 4 hops (hop1 applies norm[src]; u-space thereafter) ----
    const int ggrid = (NNODES * 8 + 255) / 256;
    k_gather<true,  false><<<ggrid, 256, 0, stream>>>(
        (const float4*)h0, (float4*)h1, rowse, col, norm, nullptr);
    k_gather<false, false><<<ggrid, 256, 0, stream>>>(
        (const float4*)h1, (float4*)h0, rowse, col, norm, nullptr);
    k_gather<false, false><<<ggrid, 256, 0, stream>>>(
        (const float4*)h0, (float4*)h1, rowse, col, norm, nullptr);
    k_gather<false, true><<<ggrid, 256, 0, stream>>>(
        (const float4*)h1, (float4*)out, rowse, col, norm, (const float4*)b);
}